// Round 3
// baseline (136.099 us; speedup 1.0000x reference)
//
#include <hip/hip_runtime.h>
#include <hip/hip_bf16.h>

// Problem constants
#define NB    8      // batch
#define NG    64     // c_inp groups (g)
#define NCI   16     // conv in channels (ci)
#define NC0   16     // conv out channels (c0)
#define NJ    64     // c_out (j)
#define IH    64
#define IW    64
#define OH    62
#define OW    62
#define IPIX  4096   // 64*64
#define OPIX  3844   // 62*62

typedef __attribute__((ext_vector_type(8))) short  short8;
typedef __attribute__((ext_vector_type(4))) short  short4v;
typedef __attribute__((ext_vector_type(4))) float  float4v;

__device__ __forceinline__ unsigned short f2bf(float f) {
    unsigned int u = __builtin_bit_cast(unsigned int, f);
    unsigned int r = (u + 0x7fffu + ((u >> 16) & 1u)) >> 16;
    return (unsigned short)r;
}

// ---------------------------------------------------------------------------
// prep: blocks 0..7 build Wm B-fragments (bf16) for mix (jt = bi>>1, kh = bi&1)
//       block 8 builds conv K-fragments Kb (K padded to 160 contraction, bf16)
// Fragment convention (16x16x32 bf16): free index = lane&15, k = (lane>>4)*8+i.
// ---------------------------------------------------------------------------
__global__ __launch_bounds__(64) void prep_kernel(const float* __restrict__ K,
                                                  const float* __restrict__ c0_,
                                                  const float* __restrict__ c1_,
                                                  const float* __restrict__ c2_,
                                                  unsigned short* __restrict__ wmb,
                                                  unsigned short* __restrict__ kb) {
    int bi = blockIdx.x;
    int l  = threadIdx.x;
    if (bi < 8) {
        int jt = bi >> 1, kh = bi & 1;
        int j = jt * 16 + (l & 15);
        int j1 = j >> 4, j2 = (j >> 2) & 3, j3 = j & 3;
        for (int i = 0; i < 8; ++i) {
            int g = kh * 32 + (l >> 4) * 8 + i;
            int i1 = g >> 4, i2 = (g >> 2) & 3, i3 = g & 3;
            float s = 0.f;
            #pragma unroll
            for (int r1 = 0; r1 < 8; ++r1) {
                float a = c0_[(i1 * 4 + j1) * 8 + r1];
                float t = 0.f;
                #pragma unroll
                for (int r2 = 0; r2 < 8; ++r2) {
                    t += c1_[((r1 * 4 + i2) * 4 + j2) * 8 + r2] *
                         c2_[(r2 * 4 + i3) * 4 + j3];
                }
                s += a * t;
            }
            wmb[(bi * 64 + l) * 8 + i] = f2bf(s);
        }
    } else {
        int c0i = l & 15, q = l >> 4;
        for (int f = 0; f < 5; ++f) {
            int tap = f * 2 + (q >> 1);  // 0..9; 9 = zero pad
            for (int i = 0; i < 8; ++i) {
                int ci = (q & 1) * 8 + i;
                float v = (tap < 9) ? K[(c0i * 16 + ci) * 9 + tap] : 0.f;
                kb[(f * 64 + l) * 8 + i] = f2bf(v);
            }
        }
    }
}

// ---------------------------------------------------------------------------
// xt: streaming transpose x[b][c][px] fp32 -> xf[b][px][chunk][ci][gi] bf16,
// where c = g*16+ci, chunk = g>>3, gi = g&7. xf row (1024 ushort per px) is
// exactly MFMA-A-fragment-ready: a0 for lane(ln,quad) = xf[px][quad][ln][0..7].
// Tile = 128 channels (one g-octet x all ci) x 256 px:
//   reads  = 128 rows x 1 KB CONTIGUOUS  (copy-regime, no gather)
//   writes = 256 px x 256 B contiguous segments
// LDS 64 KB [px 256][pc 128] with XOR swizzle pc^=((px>>2)&15)<<3 to avoid
// the stride-256B bank pathology on the scalar transpose writes.
// grid = 8b * 8coct * 16pxblk = 1024 blocks of 256.
// ---------------------------------------------------------------------------
__global__ __launch_bounds__(256) void xt_kernel(const float* __restrict__ x,
                                                 unsigned short* __restrict__ xf) {
    __shared__ unsigned short lds[256 * 128];  // 64 KB
    int t    = threadIdx.x;
    int bi   = blockIdx.x;
    int pxb  = bi & 15;
    int coct = (bi >> 4) & 7;
    int b    = bi >> 7;
    int px0  = pxb * 256;
    int wv = t >> 6, l = t & 63;

    const float* xb = x + ((size_t)(b * 1024 + coct * 128) * IPIX) + px0 + 4 * l;
    int swz = (l & 15) << 3;
    #pragma unroll 4
    for (int s = 0; s < 32; ++s) {
        int r = wv * 32 + s;                       // channel within octet: 0..127
        float4v v = *(const float4v*)(xb + (size_t)r * IPIX);
        int pc  = (r & 15) * 8 + (r >> 4);          // ci*8 + gi
        int pcs = pc ^ swz;                         // px>>2 == l for px=4l..4l+3
        #pragma unroll
        for (int p = 0; p < 4; ++p) {
            lds[(4 * l + p) * 128 + pcs] = f2bf(v[p]);
        }
    }
    __syncthreads();

    int lo = t & 15, ph = t >> 4;                   // ph 0..15
    unsigned short* ob = xf + ((size_t)(b * IPIX + px0) * 1024) + coct * 128 + lo * 8;
    for (int w = 0; w < 16; ++w) {
        int px = w * 16 + ph;
        short8 v = *(const short8*)(lds + px * 128 + ((lo ^ ((px >> 2) & 15)) * 8));
        *(short8*)(ob + (size_t)px * 1024) = v;
    }
}

// ---------------------------------------------------------------------------
// mixf: Z[P][j][ci] (bf16) = sum_g xf[P][g,ci] * Wm[g,j] via MFMA, P = b*4096+px.
// NO LDS, no barrier: a0/a1 are direct dwordx4 global loads from xf
// (1 KB contiguous per wave-instr; xf is LLC-resident, just written by xt).
// Per px: D[m=ci(16)][n=j(16/tile)], K = g (64 = 2 frags), 8 MFMA, 4x b64 Z-store.
// Values + accumulation order identical to the old LDS-staged mix2.
// grid = 1024 blocks of 256; wave = 8 px.
// ---------------------------------------------------------------------------
__global__ __launch_bounds__(256) void mixf_kernel(const unsigned short* __restrict__ xf,
                                                   const unsigned short* __restrict__ wmb,
                                                   unsigned short* __restrict__ Z) {
    int t = threadIdx.x, lane = t & 63, wv = t >> 6;
    int ln = lane & 15, quad = lane >> 4;

    short8 bf[8];
    #pragma unroll
    for (int q8 = 0; q8 < 8; ++q8)
        bf[q8] = *(const short8*)(wmb + (q8 * 64 + lane) * 8);  // [jt*2+kh]

    int P0 = blockIdx.x * 32 + wv * 8;
    const unsigned short* xr = xf + (size_t)P0 * 1024 + quad * 128 + ln * 8;
    unsigned short* zr = Z + (size_t)P0 * 1024 + ln * 16 + quad * 4;

    #pragma unroll 2
    for (int i = 0; i < 8; ++i) {
        short8 a0 = *(const short8*)(xr + (size_t)i * 1024);        // chunks 0..3 (g 0..31)
        short8 a1 = *(const short8*)(xr + (size_t)i * 1024 + 512);  // chunks 4..7 (g 32..63)
        unsigned short* zp = zr + (size_t)i * 1024;
        #pragma unroll
        for (int jt = 0; jt < 4; ++jt) {
            float4v acc = {0.f, 0.f, 0.f, 0.f};
            acc = __builtin_amdgcn_mfma_f32_16x16x32_bf16(a0, bf[jt * 2 + 0], acc, 0, 0, 0);
            acc = __builtin_amdgcn_mfma_f32_16x16x32_bf16(a1, bf[jt * 2 + 1], acc, 0, 0, 0);
            short4v o;
            o[0] = (short)f2bf(acc[0]); o[1] = (short)f2bf(acc[1]);
            o[2] = (short)f2bf(acc[2]); o[3] = (short)f2bf(acc[3]);
            *(short4v*)(zp + jt * 256) = o;
        }
    }
}

// ---------------------------------------------------------------------------
// conv2: out[b,c0,p,j] = bias[j] + sum_{ci,tap} K[c0,ci,tap] * Z[b, p+tap, j, ci]
// MFMA with A = Z (m = j), B = K (n = c0), K-dim = 160 (9 taps x 16 ci, padded).
// D rows are 4 CONSECUTIVE j per lane -> single float4 output store per lane
// per pixel. grid = 8 * 62 * 2 = 992 blocks of 256; wave = j-tile, 31 pixels.
// ---------------------------------------------------------------------------
__global__ __launch_bounds__(256, 4) void conv2_kernel(const unsigned short* __restrict__ Z,
                                                       const unsigned short* __restrict__ kb,
                                                       const float* __restrict__ bias,
                                                       float* __restrict__ out) {
    int t = threadIdx.x, lane = t & 63, wv = t >> 6;
    int ln = lane & 15, quad = lane >> 4;
    int blk = blockIdx.x;
    int xh = blk & 1;
    int y  = (blk >> 1) % OH;
    int b  = blk / (OH * 2);

    short8 af[5];
    int off[5];
    #pragma unroll
    for (int f = 0; f < 5; ++f) {
        af[f] = *(const short8*)(kb + (f * 64 + lane) * 8);
        int tap = f * 2 + (quad >> 1);
        if (tap > 8) tap = 8;              // pad chunk: K is zero, any valid addr
        int dy = tap / 3, dx = tap % 3;
        off[f] = (dy * IW + dx) * 1024 + (wv * 16 + ln) * 16 + (quad & 1) * 8;
    }
    // bias along j (acc rows): j = wv*16 + quad*4 + r
    float4v bv = *(const float4v*)(bias + wv * 16 + quad * 4);

    const unsigned short* zbase = Z + (size_t)(b * IPIX + y * IW + xh * 31) * 1024;
    // per-lane c0 = ln (acc cols); j base = wv*16 + quad*4
    float* ob = out + ((size_t)(b * NC0 + ln) * OPIX + (size_t)(y * OW + xh * 31)) * NJ
                    + wv * 16 + quad * 4;

    #pragma unroll 2
    for (int xi = 0; xi < 31; ++xi) {
        const unsigned short* zp = zbase + (size_t)xi * 1024;
        short8 z0 = *(const short8*)(zp + off[0]);
        short8 z1 = *(const short8*)(zp + off[1]);
        short8 z2 = *(const short8*)(zp + off[2]);
        short8 z3 = *(const short8*)(zp + off[3]);
        short8 z4 = *(const short8*)(zp + off[4]);
        float4v acc = bv;
        acc = __builtin_amdgcn_mfma_f32_16x16x32_bf16(z0, af[0], acc, 0, 0, 0);
        acc = __builtin_amdgcn_mfma_f32_16x16x32_bf16(z1, af[1], acc, 0, 0, 0);
        acc = __builtin_amdgcn_mfma_f32_16x16x32_bf16(z2, af[2], acc, 0, 0, 0);
        acc = __builtin_amdgcn_mfma_f32_16x16x32_bf16(z3, af[3], acc, 0, 0, 0);
        acc = __builtin_amdgcn_mfma_f32_16x16x32_bf16(z4, af[4], acc, 0, 0, 0);
        *(float4v*)(ob + (size_t)xi * NJ) = acc;
    }
}

// ---------------------------------------------------------------------------
// Fallback path (small ws): round-1 kernels, fp32 throughout.
// ---------------------------------------------------------------------------
__global__ __launch_bounds__(64) void wm_kernel(const float* __restrict__ core0,
                                                const float* __restrict__ core1,
                                                const float* __restrict__ core2,
                                                float* __restrict__ Wm) {
    int g = threadIdx.x;
    int i1 = g >> 4, i2 = (g >> 2) & 3, i3 = g & 3;
    for (int j = 0; j < NJ; ++j) {
        int j1 = j >> 4, j2 = (j >> 2) & 3, j3 = j & 3;
        float s = 0.f;
        #pragma unroll
        for (int r1 = 0; r1 < 8; ++r1) {
            float a = core0[(i1 * 4 + j1) * 8 + r1];
            float t = 0.f;
            #pragma unroll
            for (int r2 = 0; r2 < 8; ++r2) {
                t += core1[((r1 * 4 + i2) * 4 + j2) * 8 + r2] *
                     core2[(r2 * 4 + i3) * 4 + j3];
            }
            s += a * t;
        }
        Wm[g * NJ + j] = s;
    }
}

__global__ __launch_bounds__(256) void fused_fallback(const float* __restrict__ x,
                                                      const float* __restrict__ K,
                                                      const float* __restrict__ Wm,
                                                      const float* __restrict__ bias,
                                                      float* __restrict__ out) {
    __shared__ float wlds[NG * NJ];
    __shared__ float klds[NCI * 9];
    int blk  = blockIdx.x;
    int pblk = blk & 15;
    int c0   = (blk >> 4) & 15;
    int b    = blk >> 8;
    for (int i = threadIdx.x; i < NG * NJ; i += 256) wlds[i] = Wm[i];
    for (int i = threadIdx.x; i < NCI * 9; i += 256) klds[i] = K[c0 * NCI * 9 + i];
    __syncthreads();

    int pix = pblk * 256 + threadIdx.x;
    if (pix >= OPIX) return;
    int y  = pix / OW;
    int xx = pix % OW;

    float acc[NJ];
    #pragma unroll
    for (int j = 0; j < NJ; ++j) acc[j] = 0.f;

    for (int g = 0; g < NG; ++g) {
        float c = 0.f;
        const float* xb = x + ((size_t)(b * NG + g) * NCI) * IPIX;
        for (int ci = 0; ci < NCI; ++ci) {
            #pragma unroll
            for (int dy = 0; dy < 3; ++dy) {
                #pragma unroll
                for (int dx = 0; dx < 3; ++dx) {
                    c += xb[ci * IPIX + (y + dy) * IW + (xx + dx)] *
                         klds[ci * 9 + dy * 3 + dx];
                }
            }
        }
        const float4* wp = (const float4*)&wlds[g * NJ];
        #pragma unroll
        for (int j4 = 0; j4 < 16; ++j4) {
            float4 w = wp[j4];
            acc[j4 * 4 + 0] += w.x * c;
            acc[j4 * 4 + 1] += w.y * c;
            acc[j4 * 4 + 2] += w.z * c;
            acc[j4 * 4 + 3] += w.w * c;
        }
    }
    #pragma unroll
    for (int j = 0; j < NJ; ++j) {
        out[(((size_t)(b * NC0 + c0) * OPIX) + pix) * NJ + j] = acc[j] + bias[j];
    }
}

extern "C" void kernel_launch(void* const* d_in, const int* in_sizes, int n_in,
                              void* d_out, int out_size, void* d_ws, size_t ws_size,
                              hipStream_t stream) {
    const float* x     = (const float*)d_in[0];
    const float* K     = (const float*)d_in[1];
    const float* core0 = (const float*)d_in[2];
    const float* core1 = (const float*)d_in[3];
    const float* core2 = (const float*)d_in[4];
    const float* bias  = (const float*)d_in[5];
    float* out = (float*)d_out;

    const size_t z_off   = 16384;
    const size_t z_bytes = (size_t)NB * IPIX * NJ * NCI * sizeof(unsigned short);  // 67.1 MB

    if (ws_size >= z_off + 2 * z_bytes + 256) {
        unsigned short* wmb = (unsigned short*)d_ws;                    // 8 KB
        unsigned short* kb  = (unsigned short*)((char*)d_ws + 8192);    // 5 KB
        unsigned short* xf  = (unsigned short*)((char*)d_ws + z_off);
        unsigned short* Z   = (unsigned short*)((char*)d_ws + z_off + z_bytes);
        prep_kernel<<<9, 64, 0, stream>>>(K, core0, core1, core2, wmb, kb);
        xt_kernel<<<1024, 256, 0, stream>>>(x, xf);
        mixf_kernel<<<1024, 256, 0, stream>>>(xf, wmb, Z);
        conv2_kernel<<<NB * OH * 2, 256, 0, stream>>>(Z, kb, bias, out);
    } else {
        float* Wm = (float*)d_ws;
        wm_kernel<<<1, 64, 0, stream>>>(core0, core1, core2, Wm);
        fused_fallback<<<NB * NC0 * 16, 256, 0, stream>>>(x, K, Wm, bias, out);
    }
}